// Round 9
// baseline (5708.846 us; speedup 1.0000x reference)
//
#include <hip/hip_runtime.h>
#include <cstdint>
#include <cstddef>

#define Dm 768
#define Hh 12
#define DHd 64
#define Ll 12
#define Vv 50257
#define Vp 50304          // padded vocab (393*128)
#define Tt 4096
#define Ff 3072
#define QS 2304           // fused qkv row stride
#define ETA (1.0f/16.0f)

typedef __attribute__((ext_vector_type(8))) short bf16x8;
typedef __attribute__((ext_vector_type(8))) unsigned short ushort8;
typedef __attribute__((ext_vector_type(4))) float f32x4;

static __device__ __forceinline__ unsigned short f2bf(float f){
  union { float f; unsigned int u; } v; v.f = f;
  unsigned int r = v.u + 0x7fffu + ((v.u >> 16) & 1u);
  return (unsigned short)(r >> 16);
}
static __device__ __forceinline__ unsigned short f2bf_rhu(float f){
  union { float f; unsigned int u; } v; v.f = f;
  return (unsigned short)((v.u + 0x8000u) >> 16);
}
// returns (hi<<16)|lo : hi=bf16(f), lo=bf16(f - hi)
static __device__ __forceinline__ uint32_t split_bf(float f){
  const unsigned short h = f2bf(f);
  union { uint32_t u; float f; } vh; vh.u = ((uint32_t)h) << 16;
  const unsigned short l = f2bf(f - vh.f);
  return (((uint32_t)h) << 16) | (uint32_t)l;
}
// async global->LDS, 16B per lane; dest = wave-uniform base + lane*16
static __device__ __forceinline__ void gload16(const void* g, void* l){
  __builtin_amdgcn_global_load_lds((const __attribute__((address_space(1))) unsigned int*)g,
                                   (__attribute__((address_space(3))) unsigned int*)l, 16, 0, 0);
}

// ---- weight transform: f32 [L][K][Ns] -> swizzle-baked H/L ushort panels [L][K/64][Nd][64] (+coff) ----
__global__ __launch_bounds__(256)
void convwt_kernel(const float* __restrict__ src, unsigned short* __restrict__ dstH,
                   unsigned short* __restrict__ dstL, int K, int Ns, int Nd, int coff)
{
  const int l  = blockIdx.y;
  const int nb = blockIdx.x % (Ns/64);
  const int ks = blockIdx.x / (Ns/64);
  const int t  = threadIdx.x;
  __shared__ float tile[64][65];
  const float* W = src + (size_t)l*K*Ns;
  {
    const int r = t >> 2, c0 = (t & 3) * 16;
    const float* s = W + (size_t)(ks*64 + r)*Ns + nb*64 + c0;
    #pragma unroll
    for (int i = 0; i < 4; ++i) {
      const float4 f = *(const float4*)(s + i*4);
      tile[r][c0+i*4+0]=f.x; tile[r][c0+i*4+1]=f.y; tile[r][c0+i*4+2]=f.z; tile[r][c0+i*4+3]=f.w;
    }
  }
  __syncthreads();
  const int n   = t >> 2;
  const int kk0 = (t & 3) * 16;
  const int gn  = coff + nb*64 + n;
  unsigned short bh[16], bl[16];
  #pragma unroll
  for (int i = 0; i < 16; ++i) {
    const uint32_t p = split_bf(tile[kk0 + i][n]);
    bh[i] = (unsigned short)(p >> 16); bl[i] = (unsigned short)p;
  }
  const size_t rowb = ((size_t)l*K*Nd + ((size_t)ks*Nd + gn)*64) * 2;
  const int swz = (gn & 7) << 4;
  char* bH = (char*)dstH + rowb;
  char* bL = (char*)dstL + rowb;
  *(ushort8*)(bH + ((kk0*2)      ^ swz)) = *(ushort8*)&bh[0];
  *(ushort8*)(bH + ((kk0*2 + 16) ^ swz)) = *(ushort8*)&bh[8];
  *(ushort8*)(bL + ((kk0*2)      ^ swz)) = *(ushort8*)&bl[0];
  *(ushort8*)(bL + ((kk0*2 + 16) ^ swz)) = *(ushort8*)&bl[8];
}

// ---- tok f32 -> swizzle-baked bf16 panels [12][Vp][64] ----
__global__ __launch_bounds__(256)
void convtok_kernel(const float* __restrict__ src, unsigned short* __restrict__ dst)
{
  const int total = 12 * Vp * 8;
  for (int gi = blockIdx.x*256 + threadIdx.x; gi < total; gi += gridDim.x*256) {
    const int j  = gi & 7;
    const int v  = (gi >> 3) % Vp;
    const int ks = gi / (8 * Vp);
    ushort8 u;
    if (v < Vv) {
      const float* s = src + (size_t)v*Dm + ks*64 + j*8;
      const float4 f0 = *(const float4*)s, f1 = *(const float4*)(s+4);
      u[0]=f2bf(f0.x); u[1]=f2bf(f0.y); u[2]=f2bf(f0.z); u[3]=f2bf(f0.w);
      u[4]=f2bf(f1.x); u[5]=f2bf(f1.y); u[6]=f2bf(f1.z); u[7]=f2bf(f1.w);
    } else {
      #pragma unroll
      for (int q = 0; q < 8; ++q) u[q] = 0;
    }
    const size_t rowb = ((size_t)ks*Vp + v) * 128;
    *(ushort8*)((char*)dst + rowb + ((j*16) ^ ((v&7)<<4))) = u;
  }
}

// ---------------- LayerNorm; OMODE: 0=f32, 1=packed u32, 2=bf16 ushort ----------------
template<int OMODE>
__global__ __launch_bounds__(256)
void ln_kernel(const float* __restrict__ in, const int* __restrict__ ids,
               const float* __restrict__ w, const float* __restrict__ b,
               void* __restrict__ outp)
{
  const int row = blockIdx.x;
  const int t = threadIdx.x;
  const float* px = in + (ids ? (size_t)ids[row] * Dm : (size_t)row * Dm);
  float x0 = px[t], x1 = px[t+256], x2 = px[t+512];
  float s  = x0 + x1 + x2;
  float s2 = x0*x0 + x1*x1 + x2*x2;
  #pragma unroll
  for (int o = 32; o > 0; o >>= 1) { s += __shfl_xor(s, o); s2 += __shfl_xor(s2, o); }
  __shared__ float ls[4], ls2[4];
  if ((t & 63) == 0) { ls[t>>6] = s; ls2[t>>6] = s2; }
  __syncthreads();
  s  = ls[0]+ls[1]+ls[2]+ls[3];
  s2 = ls2[0]+ls2[1]+ls2[2]+ls2[3];
  const float mu  = s * (1.0f/Dm);
  const float var = s2 * (1.0f/Dm) - mu*mu;
  const float rs  = rsqrtf(var + 1e-5f);
  const float v0 = (x0-mu)*rs*w[t]     + b[t];
  const float v1 = (x1-mu)*rs*w[t+256] + b[t+256];
  const float v2 = (x2-mu)*rs*w[t+512] + b[t+512];
  if (OMODE == 0) {
    float* po = (float*)outp + (size_t)row * Dm;
    po[t] = v0; po[t+256] = v1; po[t+512] = v2;
  } else if (OMODE == 1) {
    uint32_t* po = (uint32_t*)outp + (size_t)row * Dm;
    po[t] = split_bf(v0); po[t+256] = split_bf(v1); po[t+512] = split_bf(v2);
  } else {
    unsigned short* po = (unsigned short*)outp + (size_t)row * Dm;
    po[t] = f2bf(v0); po[t+256] = f2bf(v1); po[t+512] = f2bf(v2);
  }
}

// ---------------- RoPE on fused qkv (stride QS): q at +0, k at +768 ----------------
__global__ __launch_bounds__(256)
void rope_kernel(float* __restrict__ qkv)
{
  const int gid = blockIdx.x * 256 + threadIdx.x;
  if (gid >= Tt * Hh * 32) return;
  const int tkn = gid / (Hh * 32);
  const int r   = gid - tkn * (Hh * 32);
  const int hh  = r >> 5;
  const int d   = r & 31;
  const int s   = tkn & 1023;
  const float freq = 1.0f / powf(10000.0f, (float)d * (1.0f/32.0f));
  const float ang  = (float)s * freq;
  const float c = cosf(ang), sn = sinf(ang);
  const size_t base = (size_t)tkn * QS + hh * DHd + d;
  float a1 = qkv[base], a2 = qkv[base + 32];
  qkv[base]      = a1*c - a2*sn;
  qkv[base + 32] = a1*sn + a2*c;
  float b1 = qkv[base + Dm], b2 = qkv[base + Dm + 32];
  qkv[base + Dm]      = b1*c - b2*sn;
  qkv[base + Dm + 32] = b1*sn + b2*c;
}

// ---------------- TTT chunked scan on fused qkv (stride QS); O packed to ob (stride Dm) ----------------
__global__ __launch_bounds__(256)
void ttt_scan_kernel(const float* __restrict__ qkv, uint32_t* __restrict__ ob)
{
  const int head = blockIdx.x >> 2;
  const int es   = blockIdx.x & 3;
  const int b  = head / Hh;
  const int hd = head % Hh;
  const int t  = threadIdx.x;
  __shared__ float Wm[64][17];
  __shared__ float kms[16][68];
  __shared__ float qms[16][68];
  __shared__ float Es[16][16];
  __shared__ float Asc[16][16];

  const int e   = t & 15;
  const int m16 = t >> 4;
  const int sr  = t >> 4;
  const int sc  = (t & 15) * 4;

  for (int i = t; i < 64*17; i += 256) ((float*)Wm)[i] = 0.0f;

  const int tb0 = b * 1024;
  const size_t gbase = (size_t)hd * DHd;
  float4 kr = *(const float4*)&qkv[(size_t)(tb0+sr)*QS + Dm   + gbase + sc];
  float4 qr = *(const float4*)&qkv[(size_t)(tb0+sr)*QS        + gbase + sc];
  __syncthreads();

  for (int c = 0; c < 64; ++c) {
    const int tb = tb0 + c*16;
    *(float4*)&kms[sr][sc] = kr;
    *(float4*)&qms[sr][sc] = qr;
    __syncthreads();
    if (c < 63) {
      kr = *(const float4*)&qkv[(size_t)(tb+16+sr)*QS + Dm   + gbase + sc];
      qr = *(const float4*)&qkv[(size_t)(tb+16+sr)*QS        + gbase + sc];
    }
    const float vreg = qkv[(size_t)(tb+m16)*QS + 2*Dm + gbase + es*16 + e];
    float aE = -vreg, aO = 0.0f;
    #pragma unroll
    for (int d = 0; d < 64; ++d) {
      const float w_ = Wm[d][e];
      aE += kms[m16][d] * w_;
      aO += qms[m16][d] * w_;
    }
    float aA = 0.0f;
    #pragma unroll
    for (int d = 0; d < 64; ++d) aA += qms[m16][d] * kms[e][d];
    Es[m16][e]  = aE;
    Asc[m16][e] = (e <= m16) ? (-ETA * aA) : 0.0f;
    __syncthreads();
    float acc = aO;
    #pragma unroll
    for (int n = 0; n < 16; ++n) acc += Asc[m16][n] * Es[n][e];
    ob[(size_t)(tb+m16)*Dm + gbase + es*16 + e] = split_bf(acc);
    #pragma unroll
    for (int j = 0; j < 4; ++j) {
      const int d = m16*4 + j;
      float a = 0.0f;
      #pragma unroll
      for (int m = 0; m < 16; ++m) a += kms[m][d] * Es[m][e];
      Wm[d][e] -= ETA * a;
    }
    __syncthreads();
  }
}

// ---------------- split-bf16 MFMA GEMM: A packed u32 (manual stage), B = baked H/L panels (gload_lds) ----------------
static __device__ __forceinline__ float gelu_f(float x){
  const float u = 0.7978845608028654f * (x + 0.044715f * x*x*x);
  return 0.5f * x * (1.0f + tanhf(u));
}

template<int TM, int TN, bool BIAS, bool GELU_, bool RES, bool PACKOUT>
__global__ __launch_bounds__(256)
void gemm_kernel(const uint32_t* __restrict__ A,
                 const unsigned short* __restrict__ BH, const unsigned short* __restrict__ BL,
                 const float* __restrict__ bias, const float* __restrict__ res,
                 void* __restrict__ Cp, int M, int N, int K)
{
  constexpr int FM = TM / 32;
  constexpr int FN = TN / 32;
  __shared__ __attribute__((aligned(16))) unsigned short AsH[TM*64];
  __shared__ __attribute__((aligned(16))) unsigned short AsL[TM*64];
  __shared__ __attribute__((aligned(16))) unsigned short BsH[TN*64];
  __shared__ __attribute__((aligned(16))) unsigned short BsL[TN*64];
  const int t    = threadIdx.x;
  const int lane = t & 63;
  const int fr   = lane & 15;
  const int fg   = lane >> 4;
  const int wave = t >> 6;
  const int wm   = (wave >> 1) * (TM/2);
  const int wn   = (wave & 1) * (TN/2);
  const int row0 = blockIdx.y * TM;
  const int n0   = blockIdx.x * TN;

  f32x4 acc[FM][FN];
  #pragma unroll
  for (int i = 0; i < FM; ++i)
    #pragma unroll
    for (int j = 0; j < FN; ++j)
      #pragma unroll
      for (int r = 0; r < 4; ++r) acc[i][j][r] = 0.0f;

  const int acol = (t & 3) * 16;

  for (int k0 = 0, ks = 0; k0 < K; k0 += 64, ++ks) {
    { // B: async linear copy of pre-swizzled panels
      const char* gH = (const char*)BH + (((size_t)ks*N + n0) * 64) * 2;
      const char* gL = (const char*)BL + (((size_t)ks*N + n0) * 64) * 2;
      #pragma unroll
      for (int r = 0; r < TN/32; ++r) {
        const int chunk = (r*4 + wave) * 1024;
        gload16(gH + chunk + lane*16, (char*)BsH + chunk);
        gload16(gL + chunk + lane*16, (char*)BsL + chunk);
      }
    }
    #pragma unroll
    for (int r0 = 0; r0 < TM; r0 += 64) { // A: manual stage (packed u32 -> H/L, swizzled write)
      const int arow = r0 + (t >> 2);
      const uint32_t* src = A + (size_t)(row0 + arow) * K + k0 + acol;
      #pragma unroll
      for (int i = 0; i < 2; ++i) {
        const uint4 p0 = *(const uint4*)(src + i*8);
        const uint4 p1 = *(const uint4*)(src + i*8 + 4);
        ushort8 uh, ul;
        uh[0]=(unsigned short)(p0.x>>16); ul[0]=(unsigned short)p0.x;
        uh[1]=(unsigned short)(p0.y>>16); ul[1]=(unsigned short)p0.y;
        uh[2]=(unsigned short)(p0.z>>16); ul[2]=(unsigned short)p0.z;
        uh[3]=(unsigned short)(p0.w>>16); ul[3]=(unsigned short)p0.w;
        uh[4]=(unsigned short)(p1.x>>16); ul[4]=(unsigned short)p1.x;
        uh[5]=(unsigned short)(p1.y>>16); ul[5]=(unsigned short)p1.y;
        uh[6]=(unsigned short)(p1.z>>16); ul[6]=(unsigned short)p1.z;
        uh[7]=(unsigned short)(p1.w>>16); ul[7]=(unsigned short)p1.w;
        const int byt = (arow*128 + acol*2 + i*16) ^ ((arow & 7) << 4);
        *(ushort8*)((char*)AsH + byt) = uh;
        *(ushort8*)((char*)AsL + byt) = ul;
      }
    }
    __syncthreads();
    #pragma unroll
    for (int kh = 0; kh < 2; ++kh) {
      bf16x8 ah[FM], al[FM], bh[FN], bl[FN];
      const int swz = (fr & 7) << 4;
      #pragma unroll
      for (int mt = 0; mt < FM; ++mt) {
        const int byt = ((wm + mt*16 + fr)*128 + kh*64 + fg*16) ^ swz;
        ah[mt] = *(const bf16x8*)((const char*)AsH + byt);
        al[mt] = *(const bf16x8*)((const char*)AsL + byt);
      }
      #pragma unroll
      for (int nt = 0; nt < FN; ++nt) {
        const int byt = ((wn + nt*16 + fr)*128 + kh*64 + fg*16) ^ swz;
        bh[nt] = *(const bf16x8*)((const char*)BsH + byt);
        bl[nt] = *(const bf16x8*)((const char*)BsL + byt);
      }
      #pragma unroll
      for (int mt = 0; mt < FM; ++mt)
        #pragma unroll
        for (int nt = 0; nt < FN; ++nt) {
          acc[mt][nt] = __builtin_amdgcn_mfma_f32_16x16x32_bf16(ah[mt], bh[nt], acc[mt][nt], 0, 0, 0);
          acc[mt][nt] = __builtin_amdgcn_mfma_f32_16x16x32_bf16(ah[mt], bl[nt], acc[mt][nt], 0, 0, 0);
          acc[mt][nt] = __builtin_amdgcn_mfma_f32_16x16x32_bf16(al[mt], bh[nt], acc[mt][nt], 0, 0, 0);
        }
    }
    __syncthreads();
  }

  #pragma unroll
  for (int mt = 0; mt < FM; ++mt) {
    #pragma unroll
    for (int nt = 0; nt < FN; ++nt) {
      const int col = n0 + wn + nt*16 + fr;
      const int rbase = row0 + wm + mt*16 + fg*4;
      const float bcol = BIAS ? bias[col] : 0.0f;
      #pragma unroll
      for (int r = 0; r < 4; ++r) {
        float val = acc[mt][nt][r];
        if (BIAS)  val += bcol;
        if (GELU_) val = gelu_f(val);
        const size_t off = (size_t)(rbase + r) * N + col;
        if (PACKOUT) {
          ((uint32_t*)Cp)[off] = split_bf(val);
        } else {
          if (RES) val += res[off];
          ((float*)Cp)[off] = val;
        }
      }
    }
  }
}

// ---------------- logits GEMM: 128x128, m-outer per-XCD mapping, C = hbf @ tokB^T ----------------
// PRE=1: B via gload_lds from baked tokb panels. PRE=0: manual convert from tok f32.
template<bool PRE>
__global__ __launch_bounds__(256)
void logits_kernel(const unsigned short* __restrict__ hbf, const float* __restrict__ tok,
                   const unsigned short* __restrict__ tokb, float* __restrict__ C)
{
  __shared__ __attribute__((aligned(16))) unsigned short As[128*64];
  __shared__ __attribute__((aligned(16))) unsigned short Bs[128*64];
  int bid = blockIdx.x;
  const int sbid = (bid & 7) * 1572 + (bid >> 3);   // XCD chunk swizzle; 1572 = 4*393
  const int row0 = (sbid / 393) * 128;              // m outer: XCD k owns m-tiles 4k..4k+3
  const int n0   = (sbid % 393) * 128;

  const int t    = threadIdx.x;
  const int lane = t & 63;
  const int fr   = lane & 15;
  const int fg   = lane >> 4;
  const int wave = t >> 6;
  const int wm   = (wave >> 1) * 64;
  const int wn   = (wave & 1) * 64;

  const int arow = t >> 1;
  const int ach  = (t & 1) * 32;

  f32x4 acc[4][4];
  #pragma unroll
  for (int i = 0; i < 4; ++i)
    #pragma unroll
    for (int j = 0; j < 4; ++j)
      #pragma unroll
      for (int r = 0; r < 4; ++r) acc[i][j][r] = 0.0f;

  for (int ks = 0; ks < 12; ++ks) {
    { // stage A (manual, swizzled write)
      const unsigned short* src = &hbf[(size_t)(row0 + arow) * Dm + ks*64 + ach];
      #pragma unroll
      for (int i = 0; i < 4; ++i) {
        const ushort8 u = *(const ushort8*)(src + i*8);
        const int byt = (arow*128 + (ach + i*8)*2) ^ ((arow & 7) << 4);
        *(ushort8*)((char*)As + byt) = u;
      }
    }
    if (PRE) { // stage B: async linear copy of baked panels
      const char* gB = (const char*)tokb + (((size_t)ks*Vp + n0) * 64) * 2;
      #pragma unroll
      for (int r = 0; r < 4; ++r) {
        const int chunk = (r*4 + wave) * 1024;
        gload16(gB + chunk + lane*16, (char*)Bs + chunk);
      }
    } else { // fallback: manual convert from tok f32
      const int brow = n0 + arow;
      if (brow < Vv) {
        const float* src = &tok[(size_t)brow * Dm + ks*64 + ach];
        #pragma unroll
        for (int i = 0; i < 4; ++i) {
          const float4 f0 = *(const float4*)(src + i*8);
          const float4 f1 = *(const float4*)(src + i*8 + 4);
          ushort8 u;
          u[0]=f2bf_rhu(f0.x); u[1]=f2bf_rhu(f0.y); u[2]=f2bf_rhu(f0.z); u[3]=f2bf_rhu(f0.w);
          u[4]=f2bf_rhu(f1.x); u[5]=f2bf_rhu(f1.y); u[6]=f2bf_rhu(f1.z); u[7]=f2bf_rhu(f1.w);
          const int byt = (arow*128 + (ach + i*8)*2) ^ ((arow & 7) << 4);
          *(ushort8*)((char*)Bs + byt) = u;
        }
      } else {
        ushort8 z;
        #pragma unroll
        for (int j = 0; j < 8; ++j) z[j] = 0;
        #pragma unroll
        for (int i = 0; i < 4; ++i) {
          const int byt = (arow*128 + (ach + i*8)*2) ^ ((arow & 7) << 4);
          *(ushort8*)((char*)Bs + byt) = z;
        }
      }
    }
    __syncthreads();
    #pragma unroll
    for (int kh = 0; kh < 2; ++kh) {
      bf16x8 af[4], bfr[4];
      const int swz = (fr & 7) << 4;
      #pragma unroll
      for (int mt = 0; mt < 4; ++mt)
        af[mt] = *(const bf16x8*)((const char*)As + (((wm + mt*16 + fr)*128 + kh*64 + fg*16) ^ swz));
      #pragma unroll
      for (int nt = 0; nt < 4; ++nt)
        bfr[nt] = *(const bf16x8*)((const char*)Bs + (((wn + nt*16 + fr)*128 + kh*64 + fg*16) ^ swz));
      #pragma unroll
      for (int mt = 0; mt < 4; ++mt)
        #pragma unroll
        for (int nt = 0; nt < 4; ++nt)
          acc[mt][nt] = __builtin_amdgcn_mfma_f32_16x16x32_bf16(af[mt], bfr[nt], acc[mt][nt], 0, 0, 0);
    }
    __syncthreads();
  }

  #pragma unroll
  for (int mt = 0; mt < 4; ++mt) {
    #pragma unroll
    for (int nt = 0; nt < 4; ++nt) {
      const int col = n0 + wn + nt*16 + fr;
      if (col < Vv) {
        const int rbase = row0 + wm + mt*16 + fg*4;
        #pragma unroll
        for (int r = 0; r < 4; ++r)
          C[(size_t)(rbase + r) * Vv + col] = acc[mt][nt][r];
      }
    }
  }
}

// ---------------- host-side orchestration ----------------
extern "C" void kernel_launch(void* const* d_in, const int* in_sizes, int n_in,
                              void* d_out, int out_size, void* d_ws, size_t ws_size,
                              hipStream_t stream)
{
  const int*   ids = (const int*)  d_in[0];
  const float* tok = (const float*)d_in[1];
  const float* ew  = (const float*)d_in[2];
  const float* eb  = (const float*)d_in[3];
  const float* wq  = (const float*)d_in[4];
  const float* wk  = (const float*)d_in[5];
  const float* wv  = (const float*)d_in[6];
  const float* wo  = (const float*)d_in[7];
  const float* n1w = (const float*)d_in[8];
  const float* n1b = (const float*)d_in[9];
  const float* n2w = (const float*)d_in[10];
  const float* n2b = (const float*)d_in[11];
  const float* m1w = (const float*)d_in[12];
  const float* m1b = (const float*)d_in[13];
  const float* m2w = (const float*)d_in[14];
  const float* m2b = (const float*)d_in[15];
  const float* onw = (const float*)d_in[16];
  const float* onb = (const float*)d_in[17];

  float* x = (float*)d_ws;
  float* h = x + (size_t)Tt * Dm;
  const size_t ws_need = (size_t)Tt*Dm*4*2 + (size_t)12*Vp*64*2;
  const bool pre = (ws_size >= ws_need);
  unsigned short* tokb = (unsigned short*)((char*)d_ws + (size_t)Tt*Dm*4*2);

  float* out = (float*)d_out;
  uint32_t* g   = (uint32_t*)d_out;                     // packed g [4096][3072]
  float*    qkv = out + (size_t)(1u << 24);             // [4096][2304] f32
  uint32_t* ob  = (uint32_t*)(out + (size_t)27000000u); // packed [4096][768]
  // weight planes (ushort) at byte offset 160 MB in d_out
  unsigned short* wbase = (unsigned short*)((uint32_t*)d_out + 40000000u);
  const size_t SQKV = (size_t)Ll * Dm * QS;   // 21,233,664
  const size_t SWO  = (size_t)Ll * Dm * Dm;   //  7,077,888
  const size_t SM   = (size_t)Ll * Dm * Ff;   // 28,311,552
  unsigned short* qkvH = wbase;
  unsigned short* qkvL = qkvH + SQKV;
  unsigned short* woH  = qkvL + SQKV;
  unsigned short* woL  = woH  + SWO;
  unsigned short* m1H  = woL  + SWO;
  unsigned short* m1L  = m1H  + SM;
  unsigned short* m2H  = m1L  + SM;
  unsigned short* m2L  = m2H  + SM;

  convwt_kernel<<<dim3(12*12, Ll), 256, 0, stream>>>(wq, qkvH, qkvL, Dm, Dm, QS, 0);
  convwt_kernel<<<dim3(12*12, Ll), 256, 0, stream>>>(wk, qkvH, qkvL, Dm, Dm, QS, Dm);
  convwt_kernel<<<dim3(12*12, Ll), 256, 0, stream>>>(wv, qkvH, qkvL, Dm, Dm, QS, 2*Dm);
  convwt_kernel<<<dim3(12*12, Ll), 256, 0, stream>>>(wo, woH, woL, Dm, Dm, Dm, 0);
  convwt_kernel<<<dim3(12*48, Ll), 256, 0, stream>>>(m1w, m1H, m1L, Dm, Ff, Ff, 0);
  convwt_kernel<<<dim3(48*12, Ll), 256, 0, stream>>>(m2w, m2H, m2L, Ff, Dm, Dm, 0);
  if (pre) convtok_kernel<<<2048, 256, 0, stream>>>(tok, tokb);

  ln_kernel<0><<<Tt, 256, 0, stream>>>(tok, ids, ew, eb, x);

  for (int l = 0; l < Ll; ++l) {
    ln_kernel<1><<<Tt, 256, 0, stream>>>(x, nullptr, n1w + l*Dm, n1b + l*Dm, h);
    gemm_kernel<128,128,false,false,false,false><<<dim3(QS/128, Tt/128), 256, 0, stream>>>(
        (const uint32_t*)h, qkvH + (size_t)l*Dm*QS, qkvL + (size_t)l*Dm*QS,
        nullptr, nullptr, qkv, Tt, QS, Dm);
    rope_kernel<<<6144, 256, 0, stream>>>(qkv);
    ttt_scan_kernel<<<192, 256, 0, stream>>>(qkv, ob);
    gemm_kernel<128,64,false,false,true,false><<<dim3(Dm/64, Tt/128), 256, 0, stream>>>(
        ob, woH + (size_t)l*Dm*Dm, woL + (size_t)l*Dm*Dm,
        nullptr, x, x, Tt, Dm, Dm);
    ln_kernel<1><<<Tt, 256, 0, stream>>>(x, nullptr, n2w + l*Dm, n2b + l*Dm, h);
    gemm_kernel<128,128,true,true,false,true><<<dim3(Ff/128, Tt/128), 256, 0, stream>>>(
        (const uint32_t*)h, m1H + (size_t)l*Dm*Ff, m1L + (size_t)l*Dm*Ff,
        m1b + (size_t)l*Ff, nullptr, g, Tt, Ff, Dm);
    gemm_kernel<128,64,true,false,true,false><<<dim3(Dm/64, Tt/128), 256, 0, stream>>>(
        g, m2H + (size_t)l*Ff*Dm, m2L + (size_t)l*Ff*Dm,
        m2b + (size_t)l*Dm, x, x, Tt, Dm, Ff);
  }

  ln_kernel<2><<<Tt, 256, 0, stream>>>(x, nullptr, onw, onb, h);
  if (pre)
    logits_kernel<true><<<dim3(12576, 1), 256, 0, stream>>>((const unsigned short*)h, tok, tokb, out);
  else
    logits_kernel<false><<<dim3(12576, 1), 256, 0, stream>>>((const unsigned short*)h, tok, nullptr, out);
}

// Round 10
// 5399.316 us; speedup vs baseline: 1.0573x; 1.0573x over previous
//
#include <hip/hip_runtime.h>
#include <cstdint>
#include <cstddef>

#define Dm 768
#define Hh 12
#define DHd 64
#define Ll 12
#define Vv 50257
#define Vp 50304          // padded vocab (393*128)
#define Tt 4096
#define Ff 3072
#define QS 2304           // fused qkv row stride
#define ETA (1.0f/16.0f)

typedef __attribute__((ext_vector_type(8))) short bf16x8;
typedef __attribute__((ext_vector_type(8))) unsigned short ushort8;
typedef __attribute__((ext_vector_type(4))) float f32x4;

static __device__ __forceinline__ unsigned short f2bf(float f){
  union { float f; unsigned int u; } v; v.f = f;
  unsigned int r = v.u + 0x7fffu + ((v.u >> 16) & 1u);
  return (unsigned short)(r >> 16);
}
static __device__ __forceinline__ unsigned short f2bf_rhu(float f){
  union { float f; unsigned int u; } v; v.f = f;
  return (unsigned short)((v.u + 0x8000u) >> 16);
}
// returns (hi<<16)|lo : hi=bf16(f), lo=bf16(f - hi)
static __device__ __forceinline__ uint32_t split_bf(float f){
  const unsigned short h = f2bf(f);
  union { uint32_t u; float f; } vh; vh.u = ((uint32_t)h) << 16;
  const unsigned short l = f2bf(f - vh.f);
  return (((uint32_t)h) << 16) | (uint32_t)l;
}
// async global->LDS, 16B per lane; dest = wave-uniform base + lane*16
static __device__ __forceinline__ void gload16(const void* g, void* l){
  __builtin_amdgcn_global_load_lds((const __attribute__((address_space(1))) unsigned int*)g,
                                   (__attribute__((address_space(3))) unsigned int*)l, 16, 0, 0);
}
// panel byte offset for element (row, k) of plane with M rows: ((ks*M+row)*128) + ((k*2)^((row&7)<<4))
static __device__ __forceinline__ size_t pan_off(int ks, size_t M, int row, int k){
  return ((size_t)ks*M + row)*128 + (size_t)(((k*2) ^ ((row & 7) << 4)));
}

// ---- weight transform: f32 [L][K][Ns] -> swizzle-baked H/L ushort panels [L][K/64][Nd][64] (+coff) ----
__global__ __launch_bounds__(256)
void convwt_kernel(const float* __restrict__ src, unsigned short* __restrict__ dstH,
                   unsigned short* __restrict__ dstL, int K, int Ns, int Nd, int coff)
{
  const int l  = blockIdx.y;
  const int nb = blockIdx.x % (Ns/64);
  const int ks = blockIdx.x / (Ns/64);
  const int t  = threadIdx.x;
  __shared__ float tile[64][65];
  const float* W = src + (size_t)l*K*Ns;
  {
    const int r = t >> 2, c0 = (t & 3) * 16;
    const float* s = W + (size_t)(ks*64 + r)*Ns + nb*64 + c0;
    #pragma unroll
    for (int i = 0; i < 4; ++i) {
      const float4 f = *(const float4*)(s + i*4);
      tile[r][c0+i*4+0]=f.x; tile[r][c0+i*4+1]=f.y; tile[r][c0+i*4+2]=f.z; tile[r][c0+i*4+3]=f.w;
    }
  }
  __syncthreads();
  const int n   = t >> 2;
  const int kk0 = (t & 3) * 16;
  const int gn  = coff + nb*64 + n;
  unsigned short bh[16], bl[16];
  #pragma unroll
  for (int i = 0; i < 16; ++i) {
    const uint32_t p = split_bf(tile[kk0 + i][n]);
    bh[i] = (unsigned short)(p >> 16); bl[i] = (unsigned short)p;
  }
  const size_t rowb = ((size_t)l*K*Nd + ((size_t)ks*Nd + gn)*64) * 2;
  const int swz = (gn & 7) << 4;
  char* bH = (char*)dstH + rowb;
  char* bL = (char*)dstL + rowb;
  *(ushort8*)(bH + ((kk0*2)      ^ swz)) = *(ushort8*)&bh[0];
  *(ushort8*)(bH + ((kk0*2 + 16) ^ swz)) = *(ushort8*)&bh[8];
  *(ushort8*)(bL + ((kk0*2)      ^ swz)) = *(ushort8*)&bl[0];
  *(ushort8*)(bL + ((kk0*2 + 16) ^ swz)) = *(ushort8*)&bl[8];
}

// ---- tok f32 -> swizzle-baked bf16 panels [12][Vp][64] ----
__global__ __launch_bounds__(256)
void convtok_kernel(const float* __restrict__ src, unsigned short* __restrict__ dst)
{
  const int total = 12 * Vp * 8;
  for (int gi = blockIdx.x*256 + threadIdx.x; gi < total; gi += gridDim.x*256) {
    const int j  = gi & 7;
    const int v  = (gi >> 3) % Vp;
    const int ks = gi / (8 * Vp);
    ushort8 u;
    if (v < Vv) {
      const float* s = src + (size_t)v*Dm + ks*64 + j*8;
      const float4 f0 = *(const float4*)s, f1 = *(const float4*)(s+4);
      u[0]=f2bf(f0.x); u[1]=f2bf(f0.y); u[2]=f2bf(f0.z); u[3]=f2bf(f0.w);
      u[4]=f2bf(f1.x); u[5]=f2bf(f1.y); u[6]=f2bf(f1.z); u[7]=f2bf(f1.w);
    } else {
      #pragma unroll
      for (int q = 0; q < 8; ++q) u[q] = 0;
    }
    const size_t rowb = ((size_t)ks*Vp + v) * 128;
    *(ushort8*)((char*)dst + rowb + ((j*16) ^ ((v&7)<<4))) = u;
  }
}

// ---------------- LayerNorm; OMODE: 0=f32 rows, 1=H/L panels, 2=H-only panels ----------------
template<int OMODE>
__global__ __launch_bounds__(256)
void ln_kernel(const float* __restrict__ in, const int* __restrict__ ids,
               const float* __restrict__ w, const float* __restrict__ b,
               void* __restrict__ o1, void* __restrict__ o2)
{
  const int row = blockIdx.x;
  const int t = threadIdx.x;
  const float* px = in + (ids ? (size_t)ids[row] * Dm : (size_t)row * Dm);
  float x0 = px[t], x1 = px[t+256], x2 = px[t+512];
  float s  = x0 + x1 + x2;
  float s2 = x0*x0 + x1*x1 + x2*x2;
  #pragma unroll
  for (int o = 32; o > 0; o >>= 1) { s += __shfl_xor(s, o); s2 += __shfl_xor(s2, o); }
  __shared__ float ls[4], ls2[4];
  if ((t & 63) == 0) { ls[t>>6] = s; ls2[t>>6] = s2; }
  __syncthreads();
  s  = ls[0]+ls[1]+ls[2]+ls[3];
  s2 = ls2[0]+ls2[1]+ls2[2]+ls2[3];
  const float mu  = s * (1.0f/Dm);
  const float var = s2 * (1.0f/Dm) - mu*mu;
  const float rs  = rsqrtf(var + 1e-5f);
  #pragma unroll
  for (int i = 0; i < 3; ++i) {
    const int c = t + i*256;
    const float xv = (i==0) ? x0 : (i==1) ? x1 : x2;
    const float vv_ = (xv-mu)*rs*w[c] + b[c];
    if (OMODE == 0) {
      ((float*)o1)[(size_t)row * Dm + c] = vv_;
    } else if (OMODE == 1) {
      const uint32_t p = split_bf(vv_);
      const size_t off = pan_off(c >> 6, Tt, row, c & 63);
      *(unsigned short*)((char*)o1 + off) = (unsigned short)(p >> 16);
      *(unsigned short*)((char*)o2 + off) = (unsigned short)p;
    } else {
      const size_t off = pan_off(c >> 6, Tt, row, c & 63);
      *(unsigned short*)((char*)o1 + off) = f2bf(vv_);
    }
  }
}

// ---------------- RoPE on fused qkv (stride QS): q at +0, k at +768 ----------------
__global__ __launch_bounds__(256)
void rope_kernel(float* __restrict__ qkv)
{
  const int gid = blockIdx.x * 256 + threadIdx.x;
  if (gid >= Tt * Hh * 32) return;
  const int tkn = gid / (Hh * 32);
  const int r   = gid - tkn * (Hh * 32);
  const int hh  = r >> 5;
  const int d   = r & 31;
  const int s   = tkn & 1023;
  const float freq = 1.0f / powf(10000.0f, (float)d * (1.0f/32.0f));
  const float ang  = (float)s * freq;
  const float c = cosf(ang), sn = sinf(ang);
  const size_t base = (size_t)tkn * QS + hh * DHd + d;
  float a1 = qkv[base], a2 = qkv[base + 32];
  qkv[base]      = a1*c - a2*sn;
  qkv[base + 32] = a1*sn + a2*c;
  float b1 = qkv[base + Dm], b2 = qkv[base + Dm + 32];
  qkv[base + Dm]      = b1*c - b2*sn;
  qkv[base + Dm + 32] = b1*sn + b2*c;
}

// ---------------- TTT scan on fused qkv; O written as H/L panels ----------------
__global__ __launch_bounds__(256)
void ttt_scan_kernel(const float* __restrict__ qkv,
                     unsigned short* __restrict__ obH, unsigned short* __restrict__ obL)
{
  const int head = blockIdx.x >> 2;
  const int es   = blockIdx.x & 3;
  const int b  = head / Hh;
  const int hd = head % Hh;
  const int t  = threadIdx.x;
  __shared__ float Wm[64][17];
  __shared__ float kms[16][68];
  __shared__ float qms[16][68];
  __shared__ float Es[16][16];
  __shared__ float Asc[16][16];

  const int e   = t & 15;
  const int m16 = t >> 4;
  const int sr  = t >> 4;
  const int sc  = (t & 15) * 4;

  for (int i = t; i < 64*17; i += 256) ((float*)Wm)[i] = 0.0f;

  const int tb0 = b * 1024;
  const size_t gbase = (size_t)hd * DHd;
  float4 kr = *(const float4*)&qkv[(size_t)(tb0+sr)*QS + Dm   + gbase + sc];
  float4 qr = *(const float4*)&qkv[(size_t)(tb0+sr)*QS        + gbase + sc];
  __syncthreads();

  for (int c = 0; c < 64; ++c) {
    const int tb = tb0 + c*16;
    *(float4*)&kms[sr][sc] = kr;
    *(float4*)&qms[sr][sc] = qr;
    __syncthreads();
    if (c < 63) {
      kr = *(const float4*)&qkv[(size_t)(tb+16+sr)*QS + Dm   + gbase + sc];
      qr = *(const float4*)&qkv[(size_t)(tb+16+sr)*QS        + gbase + sc];
    }
    const float vreg = qkv[(size_t)(tb+m16)*QS + 2*Dm + gbase + es*16 + e];
    float aE = -vreg, aO = 0.0f;
    #pragma unroll
    for (int d = 0; d < 64; ++d) {
      const float w_ = Wm[d][e];
      aE += kms[m16][d] * w_;
      aO += qms[m16][d] * w_;
    }
    float aA = 0.0f;
    #pragma unroll
    for (int d = 0; d < 64; ++d) aA += qms[m16][d] * kms[e][d];
    Es[m16][e]  = aE;
    Asc[m16][e] = (e <= m16) ? (-ETA * aA) : 0.0f;
    __syncthreads();
    float acc = aO;
    #pragma unroll
    for (int n = 0; n < 16; ++n) acc += Asc[m16][n] * Es[n][e];
    { // panel write: ks = hd (col = hd*64 + es*16 + e), row = tb+m16
      const uint32_t p = split_bf(acc);
      const size_t off = pan_off(hd, Tt, tb + m16, es*16 + e);
      *(unsigned short*)((char*)obH + off) = (unsigned short)(p >> 16);
      *(unsigned short*)((char*)obL + off) = (unsigned short)p;
    }
    #pragma unroll
    for (int j = 0; j < 4; ++j) {
      const int d = m16*4 + j;
      float a = 0.0f;
      #pragma unroll
      for (int m = 0; m < 16; ++m) a += kms[m][d] * Es[m][e];
      Wm[d][e] -= ETA * a;
    }
    __syncthreads();
  }
}

// ---------------- split-bf16 MFMA GEMM: A and B both H/L panels via gload_lds ----------------
// OUT: 0 = f32 rows (+RES), 1 = H/L panel planes (o1,o2; N-major ks)
static __device__ __forceinline__ float gelu_f(float x){
  const float u = 0.7978845608028654f * (x + 0.044715f * x*x*x);
  return 0.5f * x * (1.0f + tanhf(u));
}

template<int TM, int TN, bool BIAS, bool GELU_, bool RES, int OUT>
__global__ __launch_bounds__(256)
void gemm_kernel(const unsigned short* __restrict__ AH, const unsigned short* __restrict__ AL,
                 const unsigned short* __restrict__ BH, const unsigned short* __restrict__ BL,
                 const float* __restrict__ bias, const float* __restrict__ res,
                 void* __restrict__ o1, void* __restrict__ o2, int M, int N, int K)
{
  constexpr int FM = TM / 32;
  constexpr int FN = TN / 32;
  __shared__ __attribute__((aligned(16))) unsigned short AsH[TM*64];
  __shared__ __attribute__((aligned(16))) unsigned short AsL[TM*64];
  __shared__ __attribute__((aligned(16))) unsigned short BsH[TN*64];
  __shared__ __attribute__((aligned(16))) unsigned short BsL[TN*64];
  const int t    = threadIdx.x;
  const int lane = t & 63;
  const int fr   = lane & 15;
  const int fg   = lane >> 4;
  const int wave = t >> 6;
  const int wm   = (wave >> 1) * (TM/2);
  const int wn   = (wave & 1) * (TN/2);
  const int row0 = blockIdx.y * TM;
  const int n0   = blockIdx.x * TN;

  f32x4 acc[FM][FN];
  #pragma unroll
  for (int i = 0; i < FM; ++i)
    #pragma unroll
    for (int j = 0; j < FN; ++j)
      #pragma unroll
      for (int r = 0; r < 4; ++r) acc[i][j][r] = 0.0f;

  for (int ks = 0; ks*64 < K; ++ks) {
    { // B: async linear copy of panels
      const char* gH = (const char*)BH + ((size_t)ks*N + n0) * 128;
      const char* gL = (const char*)BL + ((size_t)ks*N + n0) * 128;
      #pragma unroll
      for (int r = 0; r < TN/32; ++r) {
        const int chunk = (r*4 + wave) * 1024;
        gload16(gH + chunk + lane*16, (char*)BsH + chunk);
        gload16(gL + chunk + lane*16, (char*)BsL + chunk);
      }
    }
    { // A: async linear copy of panels
      const char* gH = (const char*)AH + ((size_t)ks*M + row0) * 128;
      const char* gL = (const char*)AL + ((size_t)ks*M + row0) * 128;
      #pragma unroll
      for (int r = 0; r < TM/32; ++r) {
        const int chunk = (r*4 + wave) * 1024;
        gload16(gH + chunk + lane*16, (char*)AsH + chunk);
        gload16(gL + chunk + lane*16, (char*)AsL + chunk);
      }
    }
    __syncthreads();
    #pragma unroll
    for (int kh = 0; kh < 2; ++kh) {
      bf16x8 ah[FM], al[FM], bh[FN], bl[FN];
      const int swz = (fr & 7) << 4;
      #pragma unroll
      for (int mt = 0; mt < FM; ++mt) {
        const int byt = ((wm + mt*16 + fr)*128 + kh*64 + fg*16) ^ swz;
        ah[mt] = *(const bf16x8*)((const char*)AsH + byt);
        al[mt] = *(const bf16x8*)((const char*)AsL + byt);
      }
      #pragma unroll
      for (int nt = 0; nt < FN; ++nt) {
        const int byt = ((wn + nt*16 + fr)*128 + kh*64 + fg*16) ^ swz;
        bh[nt] = *(const bf16x8*)((const char*)BsH + byt);
        bl[nt] = *(const bf16x8*)((const char*)BsL + byt);
      }
      #pragma unroll
      for (int mt = 0; mt < FM; ++mt)
        #pragma unroll
        for (int nt = 0; nt < FN; ++nt) {
          acc[mt][nt] = __builtin_amdgcn_mfma_f32_16x16x32_bf16(ah[mt], bh[nt], acc[mt][nt], 0, 0, 0);
          acc[mt][nt] = __builtin_amdgcn_mfma_f32_16x16x32_bf16(ah[mt], bl[nt], acc[mt][nt], 0, 0, 0);
          acc[mt][nt] = __builtin_amdgcn_mfma_f32_16x16x32_bf16(al[mt], bh[nt], acc[mt][nt], 0, 0, 0);
        }
    }
    __syncthreads();
  }

  #pragma unroll
  for (int mt = 0; mt < FM; ++mt) {
    #pragma unroll
    for (int nt = 0; nt < FN; ++nt) {
      const int col = n0 + wn + nt*16 + fr;
      const int rbase = row0 + wm + mt*16 + fg*4;
      const float bcol = BIAS ? bias[col] : 0.0f;
      #pragma unroll
      for (int r = 0; r < 4; ++r) {
        float val = acc[mt][nt][r];
        if (BIAS)  val += bcol;
        if (GELU_) val = gelu_f(val);
        if (OUT == 1) {           // panel H/L output (for next GEMM's A)
          const uint32_t p = split_bf(val);
          const size_t off = pan_off(col >> 6, M, rbase + r, col & 63);
          *(unsigned short*)((char*)o1 + off) = (unsigned short)(p >> 16);
          *(unsigned short*)((char*)o2 + off) = (unsigned short)p;
        } else {
          const size_t off = (size_t)(rbase + r) * N + col;
          float v2 = val;
          if (RES) v2 += res[off];
          ((float*)o1)[off] = v2;
        }
      }
    }
  }
}

// ---------------- logits GEMM: 128x128, both sides single-plane panels via gload_lds ----------------
template<bool PRE>
__global__ __launch_bounds__(256)
void logits_kernel(const unsigned short* __restrict__ hop, const float* __restrict__ tok,
                   const unsigned short* __restrict__ tokb, float* __restrict__ C)
{
  __shared__ __attribute__((aligned(16))) unsigned short As[128*64];
  __shared__ __attribute__((aligned(16))) unsigned short Bs[128*64];
  int bid = blockIdx.x;
  bid = (bid & 7) * 1572 + (bid >> 3);       // XCD chunk swizzle (R8 mapping)
  const int n0   = (bid >> 5) * 128;         // n outer
  const int row0 = (bid & 31) * 128;         // m inner: 32 m-tiles share B panel

  const int t    = threadIdx.x;
  const int lane = t & 63;
  const int fr   = lane & 15;
  const int fg   = lane >> 4;
  const int wave = t >> 6;
  const int wm   = (wave >> 1) * 64;
  const int wn   = (wave & 1) * 64;

  const int arow = t >> 1;
  const int ach  = (t & 1) * 32;

  f32x4 acc[4][4];
  #pragma unroll
  for (int i = 0; i < 4; ++i)
    #pragma unroll
    for (int j = 0; j < 4; ++j)
      #pragma unroll
      for (int r = 0; r < 4; ++r) acc[i][j][r] = 0.0f;

  for (int ks = 0; ks < 12; ++ks) {
    { // A: async copy of h panels
      const char* gA = (const char*)hop + ((size_t)ks*Tt + row0) * 128;
      #pragma unroll
      for (int r = 0; r < 4; ++r) {
        const int chunk = (r*4 + wave) * 1024;
        gload16(gA + chunk + lane*16, (char*)As + chunk);
      }
    }
    if (PRE) { // B: async copy of baked tok panels
      const char* gB = (const char*)tokb + ((size_t)ks*Vp + n0) * 128;
      #pragma unroll
      for (int r = 0; r < 4; ++r) {
        const int chunk = (r*4 + wave) * 1024;
        gload16(gB + chunk + lane*16, (char*)Bs + chunk);
      }
    } else { // fallback: manual convert from tok f32
      const int brow = n0 + arow;
      if (brow < Vv) {
        const float* src = &tok[(size_t)brow * Dm + ks*64 + ach];
        #pragma unroll
        for (int i = 0; i < 4; ++i) {
          const float4 f0 = *(const float4*)(src + i*8);
          const float4 f1 = *(const float4*)(src + i*8 + 4);
          ushort8 u;
          u[0]=f2bf_rhu(f0.x); u[1]=f2bf_rhu(f0.y); u[2]=f2bf_rhu(f0.z); u[3]=f2bf_rhu(f0.w);
          u[4]=f2bf_rhu(f1.x); u[5]=f2bf_rhu(f1.y); u[6]=f2bf_rhu(f1.z); u[7]=f2bf_rhu(f1.w);
          const int byt = (arow*128 + (ach + i*8)*2) ^ ((arow & 7) << 4);
          *(ushort8*)((char*)Bs + byt) = u;
        }
      } else {
        ushort8 z;
        #pragma unroll
        for (int j = 0; j < 8; ++j) z[j] = 0;
        #pragma unroll
        for (int i = 0; i < 4; ++i) {
          const int byt = (arow*128 + (ach + i*8)*2) ^ ((arow & 7) << 4);
          *(ushort8*)((char*)Bs + byt) = z;
        }
      }
    }
    __syncthreads();
    #pragma unroll
    for (int kh = 0; kh < 2; ++kh) {
      bf16x8 af[4], bfr[4];
      const int swz = (fr & 7) << 4;
      #pragma unroll
      for (int mt = 0; mt < 4; ++mt)
        af[mt] = *(const bf16x8*)((const char*)As + (((wm + mt*16 + fr)*128 + kh*64 + fg*16) ^ swz));
      #pragma unroll
      for (int nt = 0; nt < 4; ++nt)
        bfr[nt] = *(const bf16x8*)((const char*)Bs + (((wn + nt*16 + fr)*128 + kh*64 + fg*16) ^ swz));
      #pragma unroll
      for (int mt = 0; mt < 4; ++mt)
        #pragma unroll
        for (int nt = 0; nt < 4; ++nt)
          acc[mt][nt] = __builtin_amdgcn_mfma_f32_16x16x32_bf16(af[mt], bfr[nt], acc[mt][nt], 0, 0, 0);
    }
    __syncthreads();
  }

  #pragma unroll
  for (int mt = 0; mt < 4; ++mt) {
    #pragma unroll
    for (int nt = 0; nt < 4; ++nt) {
      const int col = n0 + wn + nt*16 + fr;
      if (col < Vv) {
        const int rbase = row0 + wm + mt*16 + fg*4;
        #pragma unroll
        for (int r = 0; r < 4; ++r)
          C[(size_t)(rbase + r) * Vv + col] = acc[mt][nt][r];
      }
    }
  }
}

// ---------------- host-side orchestration ----------------
extern "C" void kernel_launch(void* const* d_in, const int* in_sizes, int n_in,
                              void* d_out, int out_size, void* d_ws, size_t ws_size,
                              hipStream_t stream)
{
  const int*   ids = (const int*)  d_in[0];
  const float* tok = (const float*)d_in[1];
  const float* ew  = (const float*)d_in[2];
  const float* eb  = (const float*)d_in[3];
  const float* wq  = (const float*)d_in[4];
  const float* wk  = (const float*)d_in[5];
  const float* wv  = (const float*)d_in[6];
  const float* wo  = (const float*)d_in[7];
  const float* n1w = (const float*)d_in[8];
  const float* n1b = (const float*)d_in[9];
  const float* n2w = (const float*)d_in[10];
  const float* n2b = (const float*)d_in[11];
  const float* m1w = (const float*)d_in[12];
  const float* m1b = (const float*)d_in[13];
  const float* m2w = (const float*)d_in[14];
  const float* m2b = (const float*)d_in[15];
  const float* onw = (const float*)d_in[16];
  const float* onb = (const float*)d_in[17];

  // ws: x f32 (12.6MB), hH/hL panels (6.3MB ea), ho panels (6.3MB), tokb panels (77MB, optional)
  const size_t SP = (size_t)12 * Tt * 64;          // panel plane elems (ushort) = 3.1M
  float* x = (float*)d_ws;
  unsigned short* hH = (unsigned short*)(x + (size_t)Tt * Dm);
  unsigned short* hL = hH + SP;
  unsigned short* ho = hL + SP;
  unsigned short* tokb = ho + SP;
  const size_t ws_need = (size_t)Tt*Dm*4 + SP*3*2 + (size_t)12*Vp*64*2;
  const bool pre = (ws_size >= ws_need);

  float* out = (float*)d_out;
  unsigned short* gH  = (unsigned short*)d_out;                 // [48][4096][64] = 25.2MB
  unsigned short* gL  = gH + (size_t)48 * Tt * 64;              // ends ~50.3MB
  float* qkv = (float*)((char*)d_out + (size_t)52*1024*1024);   // 37.7MB, ends ~90MB
  unsigned short* obH = (unsigned short*)((char*)d_out + (size_t)92*1024*1024);
  unsigned short* obL = obH + SP;                               // ends ~105MB
  unsigned short* wbase = (unsigned short*)((char*)d_out + (size_t)160*1024*1024);
  const size_t SQKV = (size_t)Ll * Dm * QS;
  const size_t SWO  = (size_t)Ll * Dm * Dm;
  const size_t SM   = (size_t)Ll * Dm * Ff;
  unsigned short* qkvH = wbase;
  unsigned short* qkvL = qkvH + SQKV;
  unsigned short* woH  = qkvL + SQKV;
  unsigned short* woL  = woH  + SWO;
  unsigned short* m1H  = woL  + SWO;
  unsigned short* m1L  = m1H  + SM;
  unsigned short* m2H  = m1L  + SM;
  unsigned short* m2L  = m2H  + SM;

  convwt_kernel<<<dim3(12*12, Ll), 256, 0, stream>>>(wq, qkvH, qkvL, Dm, Dm, QS, 0);
  convwt_kernel<<<dim3(12*12, Ll), 256, 0, stream>>>(wk, qkvH, qkvL, Dm, Dm, QS, Dm);
  convwt_kernel<<<dim3(12*12, Ll), 256, 0, stream>>>(wv, qkvH, qkvL, Dm, Dm, QS, 2*Dm);
  convwt_kernel<<<dim3(12*12, Ll), 256, 0, stream>>>(wo, woH, woL, Dm, Dm, Dm, 0);
  convwt_kernel<<<dim3(12*48, Ll), 256, 0, stream>>>(m1w, m1H, m1L, Dm, Ff, Ff, 0);
  convwt_kernel<<<dim3(48*12, Ll), 256, 0, stream>>>(m2w, m2H, m2L, Ff, Dm, Dm, 0);
  if (pre) convtok_kernel<<<2048, 256, 0, stream>>>(tok, tokb);

  ln_kernel<0><<<Tt, 256, 0, stream>>>(tok, ids, ew, eb, x, nullptr);

  for (int l = 0; l < Ll; ++l) {
    ln_kernel<1><<<Tt, 256, 0, stream>>>(x, nullptr, n1w + l*Dm, n1b + l*Dm, hH, hL);
    gemm_kernel<128,128,false,false,false,0><<<dim3(QS/128, Tt/128), 256, 0, stream>>>(
        hH, hL, qkvH + (size_t)l*Dm*QS, qkvL + (size_t)l*Dm*QS,
        nullptr, nullptr, qkv, nullptr, Tt, QS, Dm);
    rope_kernel<<<6144, 256, 0, stream>>>(qkv);
    ttt_scan_kernel<<<192, 256, 0, stream>>>(qkv, obH, obL);
    gemm_kernel<128,64,false,false,true,0><<<dim3(Dm/64, Tt/128), 256, 0, stream>>>(
        obH, obL, woH + (size_t)l*Dm*Dm, woL + (size_t)l*Dm*Dm,
        nullptr, x, x, nullptr, Tt, Dm, Dm);
    ln_kernel<1><<<Tt, 256, 0, stream>>>(x, nullptr, n2w + l*Dm, n2b + l*Dm, hH, hL);
    gemm_kernel<128,128,true,true,false,1><<<dim3(Ff/128, Tt/128), 256, 0, stream>>>(
        hH, hL, m1H + (size_t)l*Dm*Ff, m1L + (size_t)l*Dm*Ff,
        m1b + (size_t)l*Ff, nullptr, gH, gL, Tt, Ff, Dm);
    gemm_kernel<128,64,true,false,true,0><<<dim3(Dm/64, Tt/128), 256, 0, stream>>>(
        gH, gL, m2H + (size_t)l*Ff*Dm, m2L + (size_t)l*Ff*Dm,
        m2b + (size_t)l*Dm, x, x, nullptr, Tt, Dm, Ff);
  }

  ln_kernel<2><<<Tt, 256, 0, stream>>>(x, nullptr, onw, onb, ho, nullptr);
  if (pre)
    logits_kernel<true><<<dim3(12576, 1), 256, 0, stream>>>(ho, tok, tokb, out);
  else
    logits_kernel<false><<<dim3(12576, 1), 256, 0, stream>>>(ho, tok, nullptr, out);
}

// Round 11
// 4372.607 us; speedup vs baseline: 1.3056x; 1.2348x over previous
//
#include <hip/hip_runtime.h>
#include <cstdint>
#include <cstddef>

#define Dm 768
#define Hh 12
#define DHd 64
#define Ll 12
#define Vv 50257
#define Vp 50304          // padded vocab (393*128)
#define Tt 4096
#define Ff 3072
#define QS 2304           // fused qkv row stride
#define ETA (1.0f/16.0f)

typedef __attribute__((ext_vector_type(8))) _Float16 half8;
typedef __attribute__((ext_vector_type(8))) unsigned short ushort8;
typedef __attribute__((ext_vector_type(4))) float f32x4;

static __device__ __forceinline__ unsigned short f2h(float f){
  union { _Float16 h; unsigned short u; } c; c.h = (_Float16)f; return c.u;
}
// async global->LDS, 16B per lane; dest = wave-uniform base + lane*16
static __device__ __forceinline__ void gload16(const void* g, void* l){
  __builtin_amdgcn_global_load_lds((const __attribute__((address_space(1))) unsigned int*)g,
                                   (__attribute__((address_space(3))) unsigned int*)l, 16, 0, 0);
}
// panel byte offset for element (row, k) of plane with M rows
static __device__ __forceinline__ size_t pan_off(int ks, size_t M, int row, int k){
  return ((size_t)ks*M + row)*128 + (size_t)(((k*2) ^ ((row & 7) << 4)));
}

// ---- weight transform: f32 [L][K][Ns] -> swizzle-baked f16 panels [L][K/64][Nd][64] (+coff) ----
__global__ __launch_bounds__(256)
void convwt_kernel(const float* __restrict__ src, unsigned short* __restrict__ dst,
                   int K, int Ns, int Nd, int coff)
{
  const int l  = blockIdx.y;
  const int nb = blockIdx.x % (Ns/64);
  const int ks = blockIdx.x / (Ns/64);
  const int t  = threadIdx.x;
  __shared__ float tile[64][65];
  const float* W = src + (size_t)l*K*Ns;
  {
    const int r = t >> 2, c0 = (t & 3) * 16;
    const float* s = W + (size_t)(ks*64 + r)*Ns + nb*64 + c0;
    #pragma unroll
    for (int i = 0; i < 4; ++i) {
      const float4 f = *(const float4*)(s + i*4);
      tile[r][c0+i*4+0]=f.x; tile[r][c0+i*4+1]=f.y; tile[r][c0+i*4+2]=f.z; tile[r][c0+i*4+3]=f.w;
    }
  }
  __syncthreads();
  const int n   = t >> 2;
  const int kk0 = (t & 3) * 16;
  const int gn  = coff + nb*64 + n;
  unsigned short bh[16];
  #pragma unroll
  for (int i = 0; i < 16; ++i) bh[i] = f2h(tile[kk0 + i][n]);
  const size_t rowb = ((size_t)l*K*Nd + ((size_t)ks*Nd + gn)*64) * 2;
  const int swz = (gn & 7) << 4;
  char* bD = (char*)dst + rowb;
  *(ushort8*)(bD + ((kk0*2)      ^ swz)) = *(ushort8*)&bh[0];
  *(ushort8*)(bD + ((kk0*2 + 16) ^ swz)) = *(ushort8*)&bh[8];
}

// ---- tok f32 -> swizzle-baked f16 panels [12][Vp][64] ----
__global__ __launch_bounds__(256)
void convtok_kernel(const float* __restrict__ src, unsigned short* __restrict__ dst)
{
  const int total = 12 * Vp * 8;
  for (int gi = blockIdx.x*256 + threadIdx.x; gi < total; gi += gridDim.x*256) {
    const int j  = gi & 7;
    const int v  = (gi >> 3) % Vp;
    const int ks = gi / (8 * Vp);
    ushort8 u;
    if (v < Vv) {
      const float* s = src + (size_t)v*Dm + ks*64 + j*8;
      const float4 f0 = *(const float4*)s, f1 = *(const float4*)(s+4);
      u[0]=f2h(f0.x); u[1]=f2h(f0.y); u[2]=f2h(f0.z); u[3]=f2h(f0.w);
      u[4]=f2h(f1.x); u[5]=f2h(f1.y); u[6]=f2h(f1.z); u[7]=f2h(f1.w);
    } else {
      #pragma unroll
      for (int q = 0; q < 8; ++q) u[q] = 0;
    }
    const size_t rowb = ((size_t)ks*Vp + v) * 128;
    *(ushort8*)((char*)dst + rowb + ((j*16) ^ ((v&7)<<4))) = u;
  }
}

// ---- RoPE cos/sin table: rt[s*64 + d] = cos(s*f_d), rt[s*64+32+d] = sin, d<32 ----
__global__ __launch_bounds__(256)
void rtab_kernel(float* __restrict__ rt)
{
  const int idx = blockIdx.x*256 + threadIdx.x;
  if (idx >= 1024*64) return;
  const int s = idx >> 6, c = idx & 63, d = c & 31;
  const float freq = powf(10000.0f, -(float)d * (1.0f/32.0f));
  const float ang  = (float)s * freq;
  rt[idx] = (c < 32) ? cosf(ang) : sinf(ang);
}

// ---------------- LayerNorm; OMODE: 0=f32 rows, 1=f16 panels ----------------
template<int OMODE>
__global__ __launch_bounds__(256)
void ln_kernel(const float* __restrict__ in, const int* __restrict__ ids,
               const float* __restrict__ w, const float* __restrict__ b,
               void* __restrict__ o1)
{
  const int row = blockIdx.x;
  const int t = threadIdx.x;
  const float* px = in + (ids ? (size_t)ids[row] * Dm : (size_t)row * Dm);
  float x0 = px[t], x1 = px[t+256], x2 = px[t+512];
  float s  = x0 + x1 + x2;
  float s2 = x0*x0 + x1*x1 + x2*x2;
  #pragma unroll
  for (int o = 32; o > 0; o >>= 1) { s += __shfl_xor(s, o); s2 += __shfl_xor(s2, o); }
  __shared__ float ls[4], ls2[4];
  if ((t & 63) == 0) { ls[t>>6] = s; ls2[t>>6] = s2; }
  __syncthreads();
  s  = ls[0]+ls[1]+ls[2]+ls[3];
  s2 = ls2[0]+ls2[1]+ls2[2]+ls2[3];
  const float mu  = s * (1.0f/Dm);
  const float var = s2 * (1.0f/Dm) - mu*mu;
  const float rs  = rsqrtf(var + 1e-5f);
  #pragma unroll
  for (int i = 0; i < 3; ++i) {
    const int c = t + i*256;
    const float xv = (i==0) ? x0 : (i==1) ? x1 : x2;
    const float vv_ = (xv-mu)*rs*w[c] + b[c];
    if (OMODE == 0) {
      ((float*)o1)[(size_t)row * Dm + c] = vv_;
    } else {
      *(unsigned short*)((char*)o1 + pan_off(c >> 6, Tt, row, c & 63)) = f2h(vv_);
    }
  }
}

// ---------------- TTT scan with fused RoPE; O written as f16 panels ----------------
static __device__ __forceinline__ float4 rot4(float4 a, float4 p, float4 rc, float4 rs, bool hi){
  float4 o;
  if (hi) { o.x = p.x*rs.x + a.x*rc.x; o.y = p.y*rs.y + a.y*rc.y;
            o.z = p.z*rs.z + a.z*rc.z; o.w = p.w*rs.w + a.w*rc.w; }
  else    { o.x = a.x*rc.x - p.x*rs.x; o.y = a.y*rc.y - p.y*rs.y;
            o.z = a.z*rc.z - p.z*rs.z; o.w = a.w*rc.w - p.w*rs.w; }
  return o;
}

__global__ __launch_bounds__(256)
void ttt_scan_kernel(const float* __restrict__ qkv, const float* __restrict__ rt,
                     unsigned short* __restrict__ ob)
{
  const int head = blockIdx.x >> 2;
  const int es   = blockIdx.x & 3;
  const int b  = head / Hh;
  const int hd = head % Hh;
  const int t  = threadIdx.x;
  __shared__ float Wm[64][17];
  __shared__ float kms[16][68];
  __shared__ float qms[16][68];
  __shared__ float Es[16][16];
  __shared__ float Asc[16][16];

  const int e   = t & 15;
  const int m16 = t >> 4;
  const int sr  = t >> 4;
  const int sc  = (t & 15) * 4;
  const bool hi = (sc >= 32);

  for (int i = t; i < 64*17; i += 256) ((float*)Wm)[i] = 0.0f;

  const int tb0 = b * 1024;
  const size_t gbase = (size_t)hd * DHd;

  // prefetch + rotate chunk 0
  float4 krR, qrR;
  {
    const size_t ro = (size_t)(tb0 + sr)*QS + gbase;
    const float4 kr = *(const float4*)&qkv[ro + Dm + sc];
    const float4 kp = *(const float4*)&qkv[ro + Dm + (sc^32)];
    const float4 qr = *(const float4*)&qkv[ro + sc];
    const float4 qp = *(const float4*)&qkv[ro + (sc^32)];
    const int s0 = sr;
    const float4 rc = *(const float4*)&rt[s0*64 + (sc&31)];
    const float4 rs = *(const float4*)&rt[s0*64 + 32 + (sc&31)];
    krR = rot4(kr, kp, rc, rs, hi);
    qrR = rot4(qr, qp, rc, rs, hi);
  }
  __syncthreads();

  for (int c = 0; c < 64; ++c) {
    const int tb = tb0 + c*16;
    *(float4*)&kms[sr][sc] = krR;
    *(float4*)&qms[sr][sc] = qrR;
    __syncthreads();
    if (c < 63) {  // prefetch + rotate next chunk
      const size_t ro = (size_t)(tb + 16 + sr)*QS + gbase;
      const float4 kr = *(const float4*)&qkv[ro + Dm + sc];
      const float4 kp = *(const float4*)&qkv[ro + Dm + (sc^32)];
      const float4 qr = *(const float4*)&qkv[ro + sc];
      const float4 qp = *(const float4*)&qkv[ro + (sc^32)];
      const int sN = (c+1)*16 + sr;
      const float4 rc = *(const float4*)&rt[sN*64 + (sc&31)];
      const float4 rs = *(const float4*)&rt[sN*64 + 32 + (sc&31)];
      krR = rot4(kr, kp, rc, rs, hi);
      qrR = rot4(qr, qp, rc, rs, hi);
    }
    const float vreg = qkv[(size_t)(tb+m16)*QS + 2*Dm + gbase + es*16 + e];
    float aE = -vreg, aO = 0.0f;
    #pragma unroll
    for (int d = 0; d < 64; ++d) {
      const float w_ = Wm[d][e];
      aE += kms[m16][d] * w_;
      aO += qms[m16][d] * w_;
    }
    float aA = 0.0f;
    #pragma unroll
    for (int d = 0; d < 64; ++d) aA += qms[m16][d] * kms[e][d];
    Es[m16][e]  = aE;
    Asc[m16][e] = (e <= m16) ? (-ETA * aA) : 0.0f;
    __syncthreads();
    float acc = aO;
    #pragma unroll
    for (int n = 0; n < 16; ++n) acc += Asc[m16][n] * Es[n][e];
    *(unsigned short*)((char*)ob + pan_off(hd, Tt, tb + m16, es*16 + e)) = f2h(acc);
    #pragma unroll
    for (int j = 0; j < 4; ++j) {
      const int d = m16*4 + j;
      float a = 0.0f;
      #pragma unroll
      for (int m = 0; m < 16; ++m) a += kms[m][d] * Es[m][e];
      Wm[d][e] -= ETA * a;
    }
    __syncthreads();
  }
}

// ---------------- f16 MFMA GEMM: A and B f16 panels via gload_lds ----------------
// OUT: 0 = f32 rows (+RES), 1 = f16 panel plane
static __device__ __forceinline__ float gelu_f(float x){
  const float u = 0.7978845608028654f * (x + 0.044715f * x*x*x);
  return 0.5f * x * (1.0f + tanhf(u));
}

template<int TM, int TN, bool BIAS, bool GELU_, bool RES, int OUT>
__global__ __launch_bounds__(256)
void gemm_kernel(const unsigned short* __restrict__ A, const unsigned short* __restrict__ B,
                 const float* __restrict__ bias, const float* __restrict__ res,
                 void* __restrict__ o1, int M, int N, int K)
{
  constexpr int FM = TM / 32;
  constexpr int FN = TN / 32;
  __shared__ __attribute__((aligned(16))) unsigned short As[TM*64];
  __shared__ __attribute__((aligned(16))) unsigned short Bs[TN*64];
  const int t    = threadIdx.x;
  const int lane = t & 63;
  const int fr   = lane & 15;
  const int fg   = lane >> 4;
  const int wave = t >> 6;
  const int wm   = (wave >> 1) * (TM/2);
  const int wn   = (wave & 1) * (TN/2);
  const int row0 = blockIdx.y * TM;
  const int n0   = blockIdx.x * TN;

  f32x4 acc[FM][FN];
  #pragma unroll
  for (int i = 0; i < FM; ++i)
    #pragma unroll
    for (int j = 0; j < FN; ++j)
      #pragma unroll
      for (int r = 0; r < 4; ++r) acc[i][j][r] = 0.0f;

  for (int ks = 0; ks*64 < K; ++ks) {
    { // B: async linear copy of panel
      const char* gB = (const char*)B + ((size_t)ks*N + n0) * 128;
      #pragma unroll
      for (int r = 0; r < TN/32; ++r) {
        const int chunk = (r*4 + wave) * 1024;
        gload16(gB + chunk + lane*16, (char*)Bs + chunk);
      }
    }
    { // A: async linear copy of panel
      const char* gA = (const char*)A + ((size_t)ks*M + row0) * 128;
      #pragma unroll
      for (int r = 0; r < TM/32; ++r) {
        const int chunk = (r*4 + wave) * 1024;
        gload16(gA + chunk + lane*16, (char*)As + chunk);
      }
    }
    __syncthreads();
    #pragma unroll
    for (int kh = 0; kh < 2; ++kh) {
      half8 af[FM], bf[FN];
      const int swz = (fr & 7) << 4;
      #pragma unroll
      for (int mt = 0; mt < FM; ++mt)
        af[mt] = *(const half8*)((const char*)As + (((wm + mt*16 + fr)*128 + kh*64 + fg*16) ^ swz));
      #pragma unroll
      for (int nt = 0; nt < FN; ++nt)
        bf[nt] = *(const half8*)((const char*)Bs + (((wn + nt*16 + fr)*128 + kh*64 + fg*16) ^ swz));
      #pragma unroll
      for (int mt = 0; mt < FM; ++mt)
        #pragma unroll
        for (int nt = 0; nt < FN; ++nt)
          acc[mt][nt] = __builtin_amdgcn_mfma_f32_16x16x32_f16(af[mt], bf[nt], acc[mt][nt], 0, 0, 0);
    }
    __syncthreads();
  }

  #pragma unroll
  for (int mt = 0; mt < FM; ++mt) {
    #pragma unroll
    for (int nt = 0; nt < FN; ++nt) {
      const int col = n0 + wn + nt*16 + fr;
      const int rbase = row0 + wm + mt*16 + fg*4;
      const float bcol = BIAS ? bias[col] : 0.0f;
      #pragma unroll
      for (int r = 0; r < 4; ++r) {
        float val = acc[mt][nt][r];
        if (BIAS)  val += bcol;
        if (GELU_) val = gelu_f(val);
        if (OUT == 1) {
          *(unsigned short*)((char*)o1 + pan_off(col >> 6, M, rbase + r, col & 63)) = f2h(val);
        } else {
          const size_t off = (size_t)(rbase + r) * N + col;
          float v2 = val;
          if (RES) v2 += res[off];
          ((float*)o1)[off] = v2;
        }
      }
    }
  }
}

// ---------------- logits GEMM: 128x128, manual register-copy staging (R8 style), f16 ----------------
template<bool PRE>
__global__ __launch_bounds__(256)
void logits_kernel(const unsigned short* __restrict__ hop, const float* __restrict__ tok,
                   const unsigned short* __restrict__ tokb, float* __restrict__ C)
{
  __shared__ __attribute__((aligned(16))) unsigned short As[128*64];
  __shared__ __attribute__((aligned(16))) unsigned short Bs[128*64];
  int bid = blockIdx.x;
  bid = (bid & 7) * 1572 + (bid >> 3);       // XCD chunk swizzle
  const int n0   = (bid >> 5) * 128;         // n outer
  const int row0 = (bid & 31) * 128;         // m inner: 32 m-tiles share B panel

  const int t    = threadIdx.x;
  const int lane = t & 63;
  const int fr   = lane & 15;
  const int fg   = lane >> 4;
  const int wave = t >> 6;
  const int wm   = (wave >> 1) * 64;
  const int wn   = (wave & 1) * 64;

  const int arow = t >> 1;
  const int ach  = (t & 1) * 32;

  f32x4 acc[4][4];
  #pragma unroll
  for (int i = 0; i < 4; ++i)
    #pragma unroll
    for (int j = 0; j < 4; ++j)
      #pragma unroll
      for (int r = 0; r < 4; ++r) acc[i][j][r] = 0.0f;

  for (int ks = 0; ks < 12; ++ks) {
    { // A: register-copy of h panel (linear, swizzle baked)
      const char* gA = (const char*)hop + ((size_t)ks*Tt + row0) * 128;
      #pragma unroll
      for (int p = 0; p < 4; ++p) {
        const int off = p*4096 + t*16;
        const ushort8 u = *(const ushort8*)(gA + off);
        *(ushort8*)((char*)As + off) = u;
      }
    }
    if (PRE) { // B: register-copy of baked tok panel
      const char* gB = (const char*)tokb + ((size_t)ks*Vp + n0) * 128;
      #pragma unroll
      for (int p = 0; p < 4; ++p) {
        const int off = p*4096 + t*16;
        const ushort8 u = *(const ushort8*)(gB + off);
        *(ushort8*)((char*)Bs + off) = u;
      }
    } else { // fallback: convert from tok f32
      const int brow = n0 + arow;
      if (brow < Vv) {
        const float* src = &tok[(size_t)brow * Dm + ks*64 + ach];
        #pragma unroll
        for (int i = 0; i < 4; ++i) {
          const float4 f0 = *(const float4*)(src + i*8);
          const float4 f1 = *(const float4*)(src + i*8 + 4);
          ushort8 u;
          u[0]=f2h(f0.x); u[1]=f2h(f0.y); u[2]=f2h(f0.z); u[3]=f2h(f0.w);
          u[4]=f2h(f1.x); u[5]=f2h(f1.y); u[6]=f2h(f1.z); u[7]=f2h(f1.w);
          const int byt = (arow*128 + (ach + i*8)*2) ^ ((arow & 7) << 4);
          *(ushort8*)((char*)Bs + byt) = u;
        }
      } else {
        ushort8 z;
        #pragma unroll
        for (int j = 0; j < 8; ++j) z[j] = 0;
        #pragma unroll
        for (int i = 0; i < 4; ++i) {
          const int byt = (arow*128 + (ach + i*8)*2) ^ ((arow & 7) << 4);
          *(ushort8*)((char*)Bs + byt) = z;
        }
      }
    }
    __syncthreads();
    #pragma unroll
    for (int kh = 0; kh < 2; ++kh) {
      half8 af[4], bf[4];
      const int swz = (fr & 7) << 4;
      #pragma unroll
      for (int mt = 0; mt < 4; ++mt)
        af[mt] = *(const half8*)((const char*)As + (((wm + mt*16 + fr)*128 + kh*64 + fg*16) ^ swz));
      #pragma unroll
      for (int nt = 0; nt < 4; ++nt)
        bf[nt] = *(const half8*)((const char*)Bs + (((wn + nt*16 + fr)*128 + kh*64 + fg*16) ^ swz));
      #pragma unroll
      for (int mt = 0; mt < 4; ++mt)
        #pragma unroll
        for (int nt = 0; nt < 4; ++nt)
          acc[mt][nt] = __builtin_amdgcn_mfma_f32_16x16x32_f16(af[mt], bf[nt], acc[mt][nt], 0, 0, 0);
    }
    __syncthreads();
  }

  #pragma unroll
  for (int mt = 0; mt < 4; ++mt) {
    #pragma unroll
    for (int nt = 0; nt < 4; ++nt) {
      const int col = n0 + wn + nt*16 + fr;
      if (col < Vv) {
        const int rbase = row0 + wm + mt*16 + fg*4;
        #pragma unroll
        for (int r = 0; r < 4; ++r)
          C[(size_t)(rbase + r) * Vv + col] = acc[mt][nt][r];
      }
    }
  }
}

// ---------------- host-side orchestration ----------------
extern "C" void kernel_launch(void* const* d_in, const int* in_sizes, int n_in,
                              void* d_out, int out_size, void* d_ws, size_t ws_size,
                              hipStream_t stream)
{
  const int*   ids = (const int*)  d_in[0];
  const float* tok = (const float*)d_in[1];
  const float* ew  = (const float*)d_in[2];
  const float* eb  = (const float*)d_in[3];
  const float* wq  = (const float*)d_in[4];
  const float* wk  = (const float*)d_in[5];
  const float* wv  = (const float*)d_in[6];
  const float* wo  = (const float*)d_in[7];
  const float* n1w = (const float*)d_in[8];
  const float* n1b = (const float*)d_in[9];
  const float* n2w = (const float*)d_in[10];
  const float* n2b = (const float*)d_in[11];
  const float* m1w = (const float*)d_in[12];
  const float* m1b = (const float*)d_in[13];
  const float* m2w = (const float*)d_in[14];
  const float* m2b = (const float*)d_in[15];
  const float* onw = (const float*)d_in[16];
  const float* onb = (const float*)d_in[17];

  // ws: x f32 (12.6MB), h f16 panel (6.3MB), ho f16 panel (6.3MB), rtab (256KB), tokb (77MB)
  const size_t SP = (size_t)12 * Tt * 64;          // panel plane elems = 3.1M
  float* x = (float*)d_ws;
  unsigned short* hP = (unsigned short*)(x + (size_t)Tt * Dm);
  unsigned short* ho = hP + SP;
  float* rt = (float*)(ho + SP);
  unsigned short* tokb = (unsigned short*)(rt + 1024*64);
  const size_t ws_need = (size_t)Tt*Dm*4 + SP*2*2 + 1024*64*4 + (size_t)12*Vp*64*2;
  const bool pre = (ws_size >= ws_need);

  float* out = (float*)d_out;
  unsigned short* gP  = (unsigned short*)d_out;                  // [48][4096][64] f16 = 25.2MB
  float* qkv = (float*)((char*)d_out + (size_t)28*1024*1024);    // 37.7MB, ends ~66MB
  unsigned short* obP = (unsigned short*)((char*)d_out + (size_t)68*1024*1024); // 6.3MB
  unsigned short* wbase = (unsigned short*)((char*)d_out + (size_t)80*1024*1024);
  const size_t SQKV = (size_t)Ll * Dm * QS;
  const size_t SWO  = (size_t)Ll * Dm * Dm;
  const size_t SM   = (size_t)Ll * Dm * Ff;
  unsigned short* qkvW = wbase;
  unsigned short* woW  = qkvW + SQKV;
  unsigned short* m1W  = woW  + SWO;
  unsigned short* m2W  = m1W  + SM;

  convwt_kernel<<<dim3(12*12, Ll), 256, 0, stream>>>(wq, qkvW, Dm, Dm, QS, 0);
  convwt_kernel<<<dim3(12*12, Ll), 256, 0, stream>>>(wk, qkvW, Dm, Dm, QS, Dm);
  convwt_kernel<<<dim3(12*12, Ll), 256, 0, stream>>>(wv, qkvW, Dm, Dm, QS, 2*Dm);
  convwt_kernel<<<dim3(12*12, Ll), 256, 0, stream>>>(wo, woW, Dm, Dm, Dm, 0);
  convwt_kernel<<<dim3(12*48, Ll), 256, 0, stream>>>(m1w, m1W, Dm, Ff, Ff, 0);
  convwt_kernel<<<dim3(48*12, Ll), 256, 0, stream>>>(m2w, m2W, Ff, Dm, Dm, 0);
  rtab_kernel<<<256, 256, 0, stream>>>(rt);
  if (pre) convtok_kernel<<<2048, 256, 0, stream>>>(tok, tokb);

  ln_kernel<0><<<Tt, 256, 0, stream>>>(tok, ids, ew, eb, x);

  for (int l = 0; l < Ll; ++l) {
    ln_kernel<1><<<Tt, 256, 0, stream>>>(x, nullptr, n1w + l*Dm, n1b + l*Dm, hP);
    gemm_kernel<128,128,false,false,false,0><<<dim3(QS/128, Tt/128), 256, 0, stream>>>(
        hP, qkvW + (size_t)l*Dm*QS, nullptr, nullptr, qkv, Tt, QS, Dm);
    ttt_scan_kernel<<<192, 256, 0, stream>>>(qkv, rt, obP);
    gemm_kernel<128,64,false,false,true,0><<<dim3(Dm/64, Tt/128), 256, 0, stream>>>(
        obP, woW + (size_t)l*Dm*Dm, nullptr, x, x, Tt, Dm, Dm);
    ln_kernel<1><<<Tt, 256, 0, stream>>>(x, nullptr, n2w + l*Dm, n2b + l*Dm, hP);
    gemm_kernel<128,128,true,true,false,1><<<dim3(Ff/128, Tt/128), 256, 0, stream>>>(
        hP, m1W + (size_t)l*Dm*Ff, m1b + (size_t)l*Ff, nullptr, gP, Tt, Ff, Dm);
    gemm_kernel<128,64,true,false,true,0><<<dim3(Dm/64, Tt/128), 256, 0, stream>>>(
        gP, m2W + (size_t)l*Ff*Dm, m2b + (size_t)l*Dm, x, x, Tt, Dm, Ff);
  }

  ln_kernel<1><<<Tt, 256, 0, stream>>>(x, nullptr, onw, onb, ho);
  if (pre)
    logits_kernel<true><<<dim3(12576, 1), 256, 0, stream>>>(ho, tok, tokb, out);
  else
    logits_kernel<false><<<dim3(12576, 1), 256, 0, stream>>>(ho, tok, nullptr, out);
}